// Round 5
// baseline (705.752 us; speedup 1.0000x reference)
//
#include <hip/hip_runtime.h>
#include <hip/hip_bf16.h>

#define FLAT   2048
#define EDG    131072
#define NEF    64
#define EPA    32

typedef short  frag8  __attribute__((ext_vector_type(8)));   // 8 bf16 = 4 VGPRs
typedef float  f32x16 __attribute__((ext_vector_type(16)));  // MFMA 32x32 acc

__device__ __forceinline__ float siluf(float x){ return x / (1.f + __expf(-x)); }

__device__ __forceinline__ uint4 pack8(const float v[8]){
    union { uint4 u; __hip_bfloat16 h[8]; } r;
    #pragma unroll
    for (int i=0;i<8;i++) r.h[i] = __float2bfloat16(v[i]);
    return r.u;
}

__device__ __forceinline__ frag8 packA(float4 a, float4 b){
    union { uint4 u; __hip_bfloat16 h[8]; frag8 f; } r;
    r.h[0]=__float2bfloat16(a.x); r.h[1]=__float2bfloat16(a.y);
    r.h[2]=__float2bfloat16(a.z); r.h[3]=__float2bfloat16(a.w);
    r.h[4]=__float2bfloat16(b.x); r.h[5]=__float2bfloat16(b.y);
    r.h[6]=__float2bfloat16(b.z); r.h[7]=__float2bfloat16(b.w);
    return r.f;
}

// ---------------- tiny helpers ----------------
__global__ void k_hist(const int* __restrict__ src, int* __restrict__ cnt){
    int e = blockIdx.x*256 + threadIdx.x;
    if (e < EDG) atomicAdd(&cnt[src[e]], 1);
}

__global__ __launch_bounds__(1024) void k_scan(const int* __restrict__ cnt,
                                               int* __restrict__ off, int* __restrict__ cur){
    __shared__ int s[2048];
    const int tid = threadIdx.x;
    s[tid]      = cnt[tid];
    s[tid+1024] = cnt[tid+1024];
    __syncthreads();
    for (int d=1; d<2048; d<<=1){
        int a = (tid      >= d) ? s[tid      -d] : 0;
        int b = (tid+1024 >= d) ? s[tid+1024 -d] : 0;
        __syncthreads();
        s[tid]      += a;
        s[tid+1024] += b;
        __syncthreads();
    }
    int e0 = (tid==0) ? 0 : s[tid-1];
    int e1 = s[tid+1023];
    off[tid]      = e0;  cur[tid]      = e0;
    off[tid+1024] = e1;  cur[tid+1024] = e1;
    if (tid==0) off[2048] = s[2047];
}

__global__ void k_scatter(const int* __restrict__ src, int* __restrict__ cur,
                          int* __restrict__ elist){
    int e = blockIdx.x*256 + threadIdx.x;
    if (e < EDG){
        int p = atomicAdd(&cur[src[e]], 1);
        elist[p] = e;
    }
}

// vw_W2 (128x1152 f32, k-major) -> W2B fragment-major bf16
__global__ void k_cvtW2(const float* __restrict__ W2, __hip_bfloat16* __restrict__ W2B){
    int t = blockIdx.x*256 + threadIdx.x;
    if (t >= 36*8*512) return;
    int j    = t & 7;
    int lane = (t>>3) & 63;
    int cl   = lane & 31, half = lane >> 5;
    int kk   = t >> 9;           // tile*8+ks
    int ks   = kk & 7, tile = kk >> 3;
    int k = ks*16 + half*8 + j;
    int n = tile*32 + cl;
    W2B[t] = __float2bfloat16(W2[(size_t)k*1152 + n]);
}

// gW1 (273x128) / vw_W1 (49x128) -> frag-major bf16 (zero-padded K)
__global__ void k_cvtW1s(const float* __restrict__ gW1, const float* __restrict__ vwW1,
                         __hip_bfloat16* __restrict__ gW1B, __hip_bfloat16* __restrict__ vwW1B){
    int t = blockIdx.x*256 + threadIdx.x;
    if (t < 4*18*512){
        int j = t & 7;
        int lane = (t>>3) & 63;
        int cl = lane & 31, half = lane >> 5;
        int kk = t >> 9;                 // b*18+ks
        int ks = kk % 18, b = kk / 18;
        int k = ks*16 + half*8 + j;
        int c = b*32 + cl;
        gW1B[t] = __float2bfloat16(k < 273 ? gW1[(size_t)k*128 + c] : 0.f);
    } else if (t < 4*18*512 + 4*4*512){
        int t2 = t - 4*18*512;
        int j = t2 & 7;
        int lane = (t2>>3) & 63;
        int cl = lane & 31, half = lane >> 5;
        int kk = t2 >> 9;                // b*4+ks
        int ks = kk & 3, b = kk >> 2;
        int k = ks*16 + half*8 + j;
        int c = b*32 + cl;
        vwW1B[t2] = __float2bfloat16(k < 49 ? vwW1[(size_t)k*128 + c] : 0.f);
    }
}

// scales, parallel: one block per ef-row j
__global__ __launch_bounds__(128) void k_scales(const float* __restrict__ e_feat,
                         const float* __restrict__ W1, const float* __restrict__ b1,
                         const float* __restrict__ W2, const float* __restrict__ b2,
                         float* __restrict__ sfull){
    __shared__ float s_e[32];
    __shared__ float s_s[128];
    const int j = blockIdx.x, h = threadIdx.x;
    if (h < 32) s_e[h] = e_feat[j*32+h];
    __syncthreads();
    float a = b1[h];
    #pragma unroll
    for (int k=0;k<32;k++) a += s_e[k]*W1[k*128+h];
    s_s[h] = siluf(a);
    __syncthreads();
    if (h < 24){
        float acc = b2[h];
        #pragma unroll 16
        for (int kk=0;kk<128;kk++) acc += s_s[kk]*W2[kk*24+h];
        if (h < 16) sfull[j*40+h] = acc;
        else {
            int base = 16 + (h-16)*3;
            sfull[j*40+base+0] = acc;
            sfull[j*40+base+1] = acc;
            sfull[j*40+base+2] = acc;
        }
    }
}

// ---------------- fused edge kernel: prep + W2 GEMM + contraction ----------------
// A-fragments built in-register from direct gathers (no ginf LDS). h_full staged
// via early register prefetch (T14). LDS ~31 KB -> 4-5 blocks/CU.
__global__ __launch_bounds__(256) void k_edge_fused(
    const float* __restrict__ h_flat, const float* __restrict__ h_full,
    const int* __restrict__ z,
    const int* __restrict__ att_src, const int* __restrict__ att_dst,
    const float* __restrict__ att_dist, const float* __restrict__ att_vec,
    const float* __restrict__ z_emb_W,
    const __hip_bfloat16* __restrict__ vwW1B, const float* __restrict__ vw_b1,
    const __hip_bfloat16* __restrict__ gW1B, const float* __restrict__ gb1,
    const float* __restrict__ gW2, const float* __restrict__ gb2,
    const __hip_bfloat16* __restrict__ W2B, const float* __restrict__ b2,
    float* __restrict__ ve_out)
{
    __shared__ uint4 s_hid4[512];          // 8192 B: hid bf16, fragment order
    __shared__ uint4 s_fr[256];            // [0..127] wfrag(kc4..7), [128..255] gfrag(kc32..35); overlay t1T
    __shared__ float s_sT[32*36];          // 4608 B
    __shared__ float s_vT[48*36];          // 6912 B
    __shared__ float s_ve[EPA][40];        // 5120 B
    __shared__ float s_p[EPA][8];          // 1024 B
    __shared__ float s_sh1[EPA][3];
    __shared__ float s_env[EPA], s_gsum[EPA], s_coef[EPA];
    __shared__ int   s_src[EPA], s_dst[EPA], s_z[EPA];

    float* s_t1T = (float*)s_fr;           // overlay, valid after B2
    __hip_bfloat16* s_hid = (__hip_bfloat16*)s_hid4;

    const int tid = threadIdx.x;
    const int e0  = blockIdx.x * EPA;
    const int lane = tid & 63, cl = lane & 31, half = lane >> 5;
    const int wave = tid >> 6;

    // ---- P-1: early h_full gather into registers (lands in LDS at S4) ----
    float hfS[4], hfV[6];
    #pragma unroll
    for (int r=0;r<4;r++){
        int t = r*256+tid; int u = t&31, e = t>>5;
        hfS[r] = h_full[(size_t)att_dst[e0+e]*80 + u];
    }
    #pragma unroll
    for (int r=0;r<6;r++){
        int t = r*256+tid; int q = t%48, e = t/48;
        hfV[r] = h_full[(size_t)att_dst[e0+e]*80 + 32 + q];
    }

    // ---- P0: one wave builds per-edge scalars + rbf/isf fragment rows ----
    if (tid < EPA){
        int e  = e0 + tid;
        int sr = att_src[e], ds = att_dst[e];
        s_src[tid] = sr; s_dst[tid] = ds; s_z[tid] = z[ds];
        float d = att_dist[e];
        float isf = (sr == ds) ? 1.f : 0.f;
        float dc = fmaxf(d, 1e-8f);
        float ux = att_vec[e*3+0]/dc, uy = att_vec[e*3+1]/dc, uz = att_vec[e*3+2]/dc;
        float m = (isf > 0.f) ? 0.f : 1.7320508075688772f;
        s_sh1[tid][0] = m*uy; s_sh1[tid][1] = m*uz; s_sh1[tid][2] = m*ux;
        s_env[tid] = (d < 5.0f) ? 0.5f*(__cosf(0.6283185307179586f*d)+1.f) : 0.f;
        s_gsum[tid] = gb2[0];

        float rb[16];
        #pragma unroll
        for (int j=0;j<16;j++){
            float x = (d - (float)j*(1.f/3.f)) * 3.f;
            rb[j] = __expf(-0.5f*x*x);
        }
        float v[8];
        // wfrag kc4: [isf, rbf0..6]
        v[0]=isf;
        #pragma unroll
        for (int j=0;j<7;j++) v[1+j]=rb[j];
        s_fr[0*32+tid] = pack8(v);
        // wfrag kc5: rbf7..14
        #pragma unroll
        for (int j=0;j<8;j++) v[j]=rb[7+j];
        s_fr[1*32+tid] = pack8(v);
        // wfrag kc6: [rbf15, 0..]
        v[0]=rb[15];
        #pragma unroll
        for (int j=1;j<8;j++) v[j]=0.f;
        s_fr[2*32+tid] = pack8(v);
        // gfrag kc34: [isf, 0..]
        v[0]=isf;
        s_fr[128+2*32+tid] = pack8(v);
        // zeros: wfrag kc7, gfrag kc35
        #pragma unroll
        for (int j=0;j<8;j++) v[j]=0.f;
        s_fr[3*32+tid]       = pack8(v);
        s_fr[128+3*32+tid]   = pack8(v);
        // gfrag kc32: rbf0..7 ; kc33: rbf8..15
        #pragma unroll
        for (int j=0;j<8;j++) v[j]=rb[j];
        s_fr[128+0*32+tid] = pack8(v);
        #pragma unroll
        for (int j=0;j<8;j++) v[j]=rb[8+j];
        s_fr[128+1*32+tid] = pack8(v);
    }
    __syncthreads();   // B1

    const int c = wave*32 + cl;

    // ---- S3a: vw GEMM (K=64) -> s_hid ----
    {
        f32x16 acc;
        float bias = vw_b1[c];
        #pragma unroll
        for (int i=0;i<16;i++) acc[i] = bias;
        int zn = s_z[cl];
        #pragma unroll
        for (int ks=0;ks<4;ks++){
            frag8 afr;
            if (ks < 2){
                int kc = ks*2 + half;           // 0..3
                const float* zr = z_emb_W + (size_t)zn*32 + kc*8;
                afr = packA(*(const float4*)zr, *(const float4*)(zr+4));
            } else {
                int kc = ks*2 + half;           // 4..7
                afr = *((const frag8*)&s_fr[(kc-4)*32 + cl]);
            }
            frag8 bfr = *(const frag8*)(vwW1B + ((size_t)(wave*4+ks)*64 + lane)*8);
            acc = __builtin_amdgcn_mfma_f32_32x32x16_bf16(afr, bfr, acc, 0, 0, 0);
        }
        __hip_bfloat16* hb = s_hid + (c>>4)*512 + ((c>>3)&1)*256 + (c&7);
        #pragma unroll
        for (int r=0;r<16;r++){
            int e = 4*half + (r&3) + 8*(r>>2);
            hb[e*8] = __float2bfloat16(siluf(acc[r]));
        }
    }
    // ---- S3b: gate GEMM (K=288) -> s_gsum ----
    {
        f32x16 acc;
        float bias = gb1[c];
        #pragma unroll
        for (int i=0;i<16;i++) acc[i] = bias;
        int srcN = s_src[cl], dstN = s_dst[cl];
        #pragma unroll
        for (int ks=0;ks<16;ks++){
            int kc = ks*2 + half;               // 0..31
            int node = (ks < 8) ? srcN : dstN;
            int koff = (kc & 15)*8;
            const float* hp = h_flat + (size_t)node*128 + koff;
            frag8 afr = packA(*(const float4*)hp, *(const float4*)(hp+4));
            frag8 bfr = *(const frag8*)(gW1B + ((size_t)(wave*18+ks)*64 + lane)*8);
            acc = __builtin_amdgcn_mfma_f32_32x32x16_bf16(afr, bfr, acc, 0, 0, 0);
        }
        #pragma unroll
        for (int ks=16;ks<18;ks++){
            int kc = (ks-16)*2 + half;          // 0..3 -> gfrag row
            frag8 afr = *((const frag8*)&s_fr[128 + kc*32 + cl]);
            frag8 bfr = *(const frag8*)(gW1B + ((size_t)(wave*18+ks)*64 + lane)*8);
            acc = __builtin_amdgcn_mfma_f32_32x32x16_bf16(afr, bfr, acc, 0, 0, 0);
        }
        float w2 = gW2[c];
        #pragma unroll
        for (int r=0;r<16;r++){
            float p = siluf(acc[r]) * w2;
            p += __shfl_down(p, 16, 32);
            p += __shfl_down(p,  8, 32);
            p += __shfl_down(p,  4, 32);
            p += __shfl_down(p,  2, 32);
            p += __shfl_down(p,  1, 32);
            if (cl == 0){
                int e = 4*half + (r&3) + 8*(r>>2);
                atomicAdd(&s_gsum[e], p);
            }
        }
    }
    __syncthreads();   // B2 (hid + gsum ready; s_fr free)

    // ---- S4: coeff; stage sT/vT from prefetched regs; zero accumulators ----
    if (tid < EPA){
        float gate = 1.f/(1.f+__expf(-s_gsum[tid]));
        s_coef[tid] = s_env[tid]*gate;
    }
    #pragma unroll
    for (int r=0;r<4;r++){
        int t = r*256+tid; int u = t&31, e = t>>5;
        s_sT[u*36+e] = hfS[r];
    }
    #pragma unroll
    for (int r=0;r<6;r++){
        int t = r*256+tid; int q = t%48, e = t/48;
        s_vT[q*36+e] = hfV[r];
    }
    for (int t=tid; t<EPA*48; t+=256){
        int e = t/48, k = t%48;
        if (k < 40) s_ve[e][k] = 0.f; else s_p[e][k-40] = 0.f;
    }
    __syncthreads();   // B3

    // ---- S5: t1T from vT (overlay region) ----
    #pragma unroll
    for (int r=0;r<2;r++){
        int t = r*256+tid; int u = t>>5, e = t&31;
        s_t1T[u*36+e] = s_vT[(u*3+0)*36+e]*s_sh1[e][0]
                      + s_vT[(u*3+1)*36+e]*s_sh1[e][1]
                      + s_vT[(u*3+2)*36+e]*s_sh1[e][2];
    }
    __syncthreads();   // B4

    // ---- S6: W2 tile GEMMs + register contraction ----
    frag8 af[8];
    #pragma unroll
    for (int ks=0;ks<8;ks++)
        af[ks] = *(const frag8*)(s_hid + ks*512 + half*256 + cl*8);

    const int eoff = 4*half;
    const float RSQ3 = 0.5773502691896258f;
    const int  Tmain    = wave*8;
    const bool hasExtra = (wave >= 2);
    const int  Textra   = (wave==2) ? 32 : 34;

    auto mfma_tile = [&](int T)->f32x16{
        float bias = b2[T*32 + cl];
        f32x16 acc;
        #pragma unroll
        for (int q=0;q<16;q++) acc[q] = bias;
        const frag8* wb = (const frag8*)(W2B + (size_t)T*4096 + lane*8);
        #pragma unroll
        for (int ks=0;ks<8;ks++){
            frag8 bfr = wb[ks*64];
            acc = __builtin_amdgcn_mfma_f32_32x32x16_bf16(af[ks], bfr, acc, 0, 0, 0);
        }
        return acc;
    };

    {
        float racc[16];
        #pragma unroll
        for (int r=0;r<16;r++) racc[r] = 0.f;
        #pragma unroll 1
        for (int i=0; i<8; ++i){
            int T = Tmain + i;
            f32x16 acc = mfma_tile(T);
            const float* wb;
            if (wave < 2)        wb = &s_sT [(2*T+(cl>>4))*36 + eoff];
            else if (wave == 2)  wb = &s_t1T[(2*i+(cl>>4))*36 + eoff];
            else                 wb = &s_sT [(4*i+(cl>>3))*36 + eoff];
            #pragma unroll
            for (int g=0; g<4; g++){
                float4 w4 = *(const float4*)(wb + 8*g);
                racc[4*g+0] += acc[4*g+0]*w4.x;
                racc[4*g+1] += acc[4*g+1]*w4.y;
                racc[4*g+2] += acc[4*g+2]*w4.z;
                racc[4*g+3] += acc[4*g+3]*w4.w;
            }
        }
        if (wave < 2){
            int v = cl & 15;
            #pragma unroll
            for (int r=0;r<16;r++){
                int e = eoff + (r&3) + 8*(r>>2);
                atomicAdd(&s_ve[e][v], racc[r]);
            }
        } else if (wave == 2){
            int v = cl & 15;
            #pragma unroll
            for (int r=0;r<16;r++){
                int e = eoff + (r&3) + 8*(r>>2);
                atomicAdd(&s_ve[e][v], racc[r]*RSQ3);
            }
        } else {
            int v = cl & 7;
            #pragma unroll
            for (int r=0;r<16;r++){
                int e = eoff + (r&3) + 8*(r>>2);
                atomicAdd(&s_p[e][v], racc[r]);
            }
        }
    }

    if (hasExtra){
        float r3[16][3];
        #pragma unroll
        for (int r=0;r<16;r++){ r3[r][0]=0.f; r3[r][1]=0.f; r3[r][2]=0.f; }
        const int t0 = (wave==2) ? 0 : 2;
        #pragma unroll 1
        for (int tt=0; tt<2; ++tt){
            f32x16 acc = mfma_tile(Textra + tt);
            int u = 4*(t0+tt) + (cl>>3);
            #pragma unroll
            for (int i3=0;i3<3;i3++){
                const float* vb = &s_vT[(u*3+i3)*36 + eoff];
                #pragma unroll
                for (int g=0; g<4; g++){
                    float4 w4 = *(const float4*)(vb + 8*g);
                    r3[4*g+0][i3] += acc[4*g+0]*w4.x;
                    r3[4*g+1][i3] += acc[4*g+1]*w4.y;
                    r3[4*g+2][i3] += acc[4*g+2]*w4.z;
                    r3[4*g+3][i3] += acc[4*g+3]*w4.w;
                }
            }
        }
        int v = cl & 7;
        #pragma unroll
        for (int r=0;r<16;r++){
            int e = eoff + (r&3) + 8*(r>>2);
            atomicAdd(&s_ve[e][16+v*3+0], r3[r][0]);
            atomicAdd(&s_ve[e][16+v*3+1], r3[r][1]);
            atomicAdd(&s_ve[e][16+v*3+2], r3[r][2]);
        }
    }
    __syncthreads();   // B5

    // ---- S7: flush (plain coalesced stores) ----
    float* veb = ve_out + (size_t)e0*40;
    const float RFAN = 0.14433756729740643f; // 1/sqrt(48)
    #pragma unroll
    for (int r=0;r<5;r++){
        int t = r*256+tid; int e = t/40, s = t%40;
        float val;
        if (s < 16) val = s_ve[e][s];
        else {
            int v = (s-16)/3, i3 = (s-16)%3;
            val = s_p[e][v]*s_sh1[e][i3] + s_ve[e][s];
        }
        veb[t] = val * RFAN * s_coef[e];
    }
}

// ---------------- K2: per-node gather + output MLP (fused) ----------------
__global__ __launch_bounds__(256) void k_out(
    const float* __restrict__ ve, const int* __restrict__ off, const int* __restrict__ elist,
    const float* __restrict__ sfull,
    const float* __restrict__ W1, const float* __restrict__ b1,
    const float* __restrict__ W2, const float* __restrict__ b2,
    const float* __restrict__ W3, const float* __restrict__ b3,
    float* __restrict__ out)
{
    __shared__ float s_part[6][40];
    __shared__ float s_irr[40];
    __shared__ float s_inv[64][24];
    __shared__ float s_x[64][128];

    const int tid = threadIdx.x;
    const int n   = blockIdx.x;

    {
        const int o0 = off[n], o1 = off[n+1];
        int c = tid/40, s = tid - c*40;
        if (c < 6){
            float acc = 0.f;
            for (int i = o0 + c; i < o1; i += 6){
                int e = elist[i];
                acc += ve[(size_t)e*40 + s];
            }
            s_part[c][s] = acc;
        }
    }
    __syncthreads();
    if (tid < 40){
        s_irr[tid] = s_part[0][tid]+s_part[1][tid]+s_part[2][tid]
                   + s_part[3][tid]+s_part[4][tid]+s_part[5][tid];
    }
    __syncthreads();

    #pragma unroll
    for (int r=0;r<6;r++){
        int t = r*256+tid; int j = t/24, c = t%24;
        float v;
        if (c < 16) v = s_irr[c]*sfull[j*40+c];
        else {
            int base = 16 + (c-16)*3;
            float ss = 1e-12f;
            #pragma unroll
            for (int i=0;i<3;i++){ float x = s_irr[base+i]*sfull[j*40+base+i]; ss += x*x; }
            v = sqrtf(ss);
        }
        s_inv[j][c] = v;
    }
    __syncthreads();

    const int h4 = (tid & 31)*4, jg = tid >> 5;
    float acc[8][4];

    #pragma unroll
    for (int jj=0;jj<8;jj++)
        #pragma unroll
        for (int hh=0;hh<4;hh++) acc[jj][hh] = b1[h4+hh];
    #pragma unroll
    for (int k=0;k<24;k+=4){
        float4 w0 = *(const float4*)&W1[(k+0)*128+h4];
        float4 w1 = *(const float4*)&W1[(k+1)*128+h4];
        float4 w2 = *(const float4*)&W1[(k+2)*128+h4];
        float4 w3 = *(const float4*)&W1[(k+3)*128+h4];
        #pragma unroll
        for (int jj=0;jj<8;jj++){
            float4 xv = *(const float4*)&s_inv[jg*8+jj][k];
            acc[jj][0] += xv.x*w0.x + xv.y*w1.x + xv.z*w2.x + xv.w*w3.x;
            acc[jj][1] += xv.x*w0.y + xv.y*w1.y + xv.z*w2.y + xv.w*w3.y;
            acc[jj][2] += xv.x*w0.z + xv.y*w1.z + xv.z*w2.z + xv.w*w3.z;
            acc[jj][3] += xv.x*w0.w + xv.y*w1.w + xv.z*w2.w + xv.w*w3.w;
        }
    }
    #pragma unroll
    for (int jj=0;jj<8;jj++)
        *(float4*)&s_x[jg*8+jj][h4] = make_float4(siluf(acc[jj][0]), siluf(acc[jj][1]),
                                                  siluf(acc[jj][2]), siluf(acc[jj][3]));
    __syncthreads();

    #pragma unroll
    for (int jj=0;jj<8;jj++)
        #pragma unroll
        for (int hh=0;hh<4;hh++) acc[jj][hh] = b2[h4+hh];
    for (int k=0;k<128;k+=4){
        float4 w0 = *(const float4*)&W2[(k+0)*128+h4];
        float4 w1 = *(const float4*)&W2[(k+1)*128+h4];
        float4 w2 = *(const float4*)&W2[(k+2)*128+h4];
        float4 w3 = *(const float4*)&W2[(k+3)*128+h4];
        #pragma unroll
        for (int jj=0;jj<8;jj++){
            float4 xv = *(const float4*)&s_x[jg*8+jj][k];
            acc[jj][0] += xv.x*w0.x + xv.y*w1.x + xv.z*w2.x + xv.w*w3.x;
            acc[jj][1] += xv.x*w0.y + xv.y*w1.y + xv.z*w2.y + xv.w*w3.y;
            acc[jj][2] += xv.x*w0.z + xv.y*w1.z + xv.z*w2.z + xv.w*w3.z;
            acc[jj][3] += xv.x*w0.w + xv.y*w1.w + xv.z*w2.w + xv.w*w3.w;
        }
    }
    __syncthreads();
    #pragma unroll
    for (int jj=0;jj<8;jj++)
        *(float4*)&s_x[jg*8+jj][h4] = make_float4(siluf(acc[jj][0]), siluf(acc[jj][1]),
                                                  siluf(acc[jj][2]), siluf(acc[jj][3]));
    __syncthreads();

    #pragma unroll
    for (int jj=0;jj<8;jj++)
        #pragma unroll
        for (int hh=0;hh<4;hh++) acc[jj][hh] = b3[h4+hh];
    for (int k=0;k<128;k+=4){
        float4 w0 = *(const float4*)&W3[(k+0)*128+h4];
        float4 w1 = *(const float4*)&W3[(k+1)*128+h4];
        float4 w2 = *(const float4*)&W3[(k+2)*128+h4];
        float4 w3 = *(const float4*)&W3[(k+3)*128+h4];
        #pragma unroll
        for (int jj=0;jj<8;jj++){
            float4 xv = *(const float4*)&s_x[jg*8+jj][k];
            acc[jj][0] += xv.x*w0.x + xv.y*w1.x + xv.z*w2.x + xv.w*w3.x;
            acc[jj][1] += xv.x*w0.y + xv.y*w1.y + xv.z*w2.y + xv.w*w3.y;
            acc[jj][2] += xv.x*w0.z + xv.y*w1.z + xv.z*w2.z + xv.w*w3.z;
            acc[jj][3] += xv.x*w0.w + xv.y*w1.w + xv.z*w2.w + xv.w*w3.w;
        }
    }
    #pragma unroll
    for (int jj=0;jj<8;jj++){
        int j = jg*8+jj;
        *(float4*)&out[((size_t)n*64 + j)*128 + h4] =
            make_float4(acc[jj][0], acc[jj][1], acc[jj][2], acc[jj][3]);
    }
}

// ---------------- launch ----------------
extern "C" void kernel_launch(void* const* d_in, const int* in_sizes, int n_in,
                              void* d_out, int out_size, void* d_ws, size_t ws_size,
                              hipStream_t stream)
{
    const float* h        = (const float*)d_in[0];
    const float* h_full   = (const float*)d_in[1];
    const float* e_feat   = (const float*)d_in[2];
    const float* att_dist = (const float*)d_in[3];
    const float* att_vec  = (const float*)d_in[4];
    const int*   z        = (const int*)d_in[5];
    const int* att_src    = (const int*)d_in[7];
    const int* att_dst    = (const int*)d_in[8];
    const float* z_emb_W  = (const float*)d_in[9];
    const float* vw_W1    = (const float*)d_in[10];
    const float* vw_b1    = (const float*)d_in[11];
    const float* vw_W2    = (const float*)d_in[12];
    const float* vw_b2    = (const float*)d_in[13];
    const float* gW1      = (const float*)d_in[14];
    const float* gb1      = (const float*)d_in[15];
    const float* gW2      = (const float*)d_in[16];
    const float* gb2      = (const float*)d_in[17];
    const float* emW1     = (const float*)d_in[18];
    const float* emb1     = (const float*)d_in[19];
    const float* emW2     = (const float*)d_in[20];
    const float* emb2     = (const float*)d_in[21];
    const float* oW1      = (const float*)d_in[22];
    const float* ob1      = (const float*)d_in[23];
    const float* oW2      = (const float*)d_in[24];
    const float* ob2      = (const float*)d_in[25];
    const float* oW3      = (const float*)d_in[26];
    const float* ob3      = (const float*)d_in[27];
    float* out = (float*)d_out;

    char* ws = (char*)d_ws;
    float* ve    = (float*)ws;                                   // EDG*40*4 = 20.97 MB
    float* sfull = ve + (size_t)EDG*40;                          // 10 KB
    __hip_bfloat16* W2B   = (__hip_bfloat16*)(sfull + (size_t)NEF*40); // 294,912 B
    __hip_bfloat16* gW1B  = W2B  + (size_t)36*8*512;             // 73,728 B
    __hip_bfloat16* vwW1B = gW1B + (size_t)4*18*512;             // 16,384 B
    int* cnt   = (int*)(vwW1B + (size_t)4*4*512);                // 8 KB
    int* off   = cnt + 2048;
    int* cur   = off + 2049;
    int* elist = cur + 2048;                                     // 512 KB

    hipMemsetAsync(cnt, 0, 2048*sizeof(int), stream);
    k_hist    <<<EDG/256, 256, 0, stream>>>(att_src, cnt);
    k_scan    <<<1, 1024, 0, stream>>>(cnt, off, cur);
    k_scatter <<<EDG/256, 256, 0, stream>>>(att_src, cur, elist);
    k_cvtW2 <<<(36*8*512 + 255)/256, 256, 0, stream>>>(vw_W2, W2B);
    k_cvtW1s<<<(4*18*512 + 4*4*512 + 255)/256, 256, 0, stream>>>(gW1, vw_W1, gW1B, vwW1B);
    k_scales<<<NEF, 128, 0, stream>>>(e_feat, emW1, emb1, emW2, emb2, sfull);
    k_edge_fused<<<EDG/EPA, 256, 0, stream>>>(h, h_full, z, att_src, att_dst,
        att_dist, att_vec, z_emb_W, vwW1B, vw_b1, gW1B, gb1, gW2, gb2,
        W2B, vw_b2, ve);
    k_out<<<FLAT, 256, 0, stream>>>(ve, off, elist, sfull,
        oW1, ob1, oW2, ob2, oW3, ob3, out);
}